// Round 1
// baseline (2265.354 us; speedup 1.0000x reference)
//
#include <hip/hip_runtime.h>
#include <math.h>

// Problem constants (B=8 batches, N=M=2048 points, D=3)
#define BATCH 8
#define NPTS 2048
#define KITER (NPTS / 64)      // 32 columns per lane
#define ROWS_PER_BLOCK 32
#define THREADS 256
#define LOG_M 7.62559580411076f  // log(2048), double-rounded to float

// One "softmin pass": for each of 4 potential types, each batch, compute
//   f_i = 0.5*|x_i|^2 - eps * LSE_j( hh_j + x_i . (y_j/eps) )
// where hh_j = pot_j/eps - log(M) - 0.5*|y_j|^2/eps.
// Types: 0: rows=x cols=y h=g_ab out=f_ba
//        1: rows=y cols=x h=f_ba out=g_ab
//        2: rows=x cols=x h=f_aa out=f_aa
//        3: rows=y cols=y h=g_bb out=g_bb
// avg=1: out = 0.5*(old + new)  (Sinkhorn damped update); avg=0: out = new.
__global__ __launch_bounds__(THREADS, 4) void softmin_pass(
    const float* __restrict__ x, const float* __restrict__ y,
    const float* __restrict__ potSrc, float* __restrict__ potDst,
    float eps, float inv_eps, int avg)
{
    __shared__ float4 cols[NPTS];   // 32 KB: (yx*ie, yy*ie, yz*ie, hh)

    const int type  = blockIdx.z;
    const int batch = blockIdx.y;

    const float* rowP;
    const float* colP;
    int hslot, oslot;
    if (type == 0)      { rowP = x; colP = y; hslot = 1; oslot = 0; }
    else if (type == 1) { rowP = y; colP = x; hslot = 0; oslot = 1; }
    else if (type == 2) { rowP = x; colP = x; hslot = 2; oslot = 2; }
    else                { rowP = y; colP = y; hslot = 3; oslot = 3; }

    rowP += batch * NPTS * 3;
    colP += batch * NPTS * 3;
    const float* hP   = potSrc + (hslot * BATCH + batch) * NPTS;
    const float* oldP = potSrc + (oslot * BATCH + batch) * NPTS;
    float*       outP = potDst + (oslot * BATCH + batch) * NPTS;

    // Stage columns into LDS, pre-scaled by 1/eps, with fused hh.
    for (int j = threadIdx.x; j < NPTS; j += THREADS) {
        float c0 = colP[3 * j + 0];
        float c1 = colP[3 * j + 1];
        float c2 = colP[3 * j + 2];
        float hh = hP[j] * inv_eps - LOG_M
                 - 0.5f * inv_eps * (c0 * c0 + c1 * c1 + c2 * c2);
        cols[j] = make_float4(c0 * inv_eps, c1 * inv_eps, c2 * inv_eps, hh);
    }
    __syncthreads();

    const int lane = threadIdx.x & 63;
    const int wave = threadIdx.x >> 6;
    const int rowBase = blockIdx.x * ROWS_PER_BLOCK;

    for (int r = wave; r < ROWS_PER_BLOCK; r += (THREADS / 64)) {
        const int i = rowBase + r;
        const float x0 = rowP[3 * i + 0];
        const float x1v = rowP[3 * i + 1];
        const float x2v = rowP[3 * i + 2];

        float args[KITER];
        float m = -INFINITY;
        #pragma unroll
        for (int k = 0; k < KITER; ++k) {
            float4 c = cols[lane + 64 * k];
            float a = __builtin_fmaf(x0, c.x,
                        __builtin_fmaf(x1v, c.y,
                          __builtin_fmaf(x2v, c.z, c.w)));
            args[k] = a;
            m = fmaxf(m, a);
        }
        // wave-wide max (64 lanes)
        #pragma unroll
        for (int off = 32; off >= 1; off >>= 1)
            m = fmaxf(m, __shfl_xor(m, off, 64));

        float s = 0.0f;
        #pragma unroll
        for (int k = 0; k < KITER; ++k)
            s += __expf(args[k] - m);
        // wave-wide sum
        #pragma unroll
        for (int off = 32; off >= 1; off >>= 1)
            s += __shfl_xor(s, off, 64);

        if (lane == 0) {
            float xsq = x0 * x0 + x1v * x1v + x2v * x2v;
            float res = 0.5f * xsq - eps * (m + logf(s));
            outP[i] = avg ? 0.5f * (oldP[i] + res) : res;
        }
    }
}

// out[b] = (1/N) * sum_i (f_ba - f_aa) + (1/M) * sum_j (g_ab - g_bb)
__global__ void reduce_out(const float* __restrict__ pot, float* __restrict__ out)
{
    const int batch = blockIdx.x;
    const float* fba = pot + (0 * BATCH + batch) * NPTS;
    const float* gab = pot + (1 * BATCH + batch) * NPTS;
    const float* faa = pot + (2 * BATCH + batch) * NPTS;
    const float* gbb = pot + (3 * BATCH + batch) * NPTS;

    float s = 0.0f;
    for (int i = threadIdx.x; i < NPTS; i += blockDim.x)
        s += (fba[i] - faa[i]) + (gab[i] - gbb[i]);

    #pragma unroll
    for (int off = 32; off >= 1; off >>= 1)
        s += __shfl_xor(s, off, 64);

    __shared__ float red[THREADS / 64];
    const int lane = threadIdx.x & 63;
    const int wave = threadIdx.x >> 6;
    if (lane == 0) red[wave] = s;
    __syncthreads();
    if (threadIdx.x == 0) {
        float t = 0.0f;
        for (int w = 0; w < THREADS / 64; ++w) t += red[w];
        out[batch] = t * (1.0f / NPTS);
    }
}

extern "C" void kernel_launch(void* const* d_in, const int* in_sizes, int n_in,
                              void* d_out, int out_size, void* d_ws, size_t ws_size,
                              hipStream_t stream)
{
    const float* x = (const float*)d_in[0];
    const float* y = (const float*)d_in[1];
    float* out = (float*)d_out;

    // Ping-pong potential buffers in workspace: [4 slots][B][NPTS] each.
    const size_t potElems = (size_t)4 * BATCH * NPTS;
    float* P0 = (float*)d_ws;
    float* P1 = P0 + potElems;

    // Zero the initial potentials (h = a_log exactly at init).
    hipMemsetAsync(P0, 0, potElems * sizeof(float), stream);

    // Epsilon schedule: [diam^p] + exp(arange(p ln diam, p ln blur, p ln scale)) + [blur^p]
    double epsl[16];
    int ne = 0;
    epsl[ne++] = 4.0;                       // diameter^2
    const double stop = 2.0 * log(0.05);
    const double step = 2.0 * log(0.5);
    for (double e = 2.0 * log(2.0); e > stop; e += step)
        epsl[ne++] = exp(e);                // 4, 1, 0.25, 0.0625, 0.015625, 0.00390625
    epsl[ne++] = 0.05 * 0.05;               // blur^2 = 0.0025
    // Passes: init(eps[0], avg=0), loop over all ne eps (avg=1), final(eps[ne-1], avg=0)

    float* src = P0;
    float* dst = P1;
    dim3 grid(NPTS / ROWS_PER_BLOCK, BATCH, 4);

    auto launch = [&](double eps, int avg) {
        softmin_pass<<<grid, THREADS, 0, stream>>>(
            x, y, src, dst, (float)eps, (float)(1.0 / eps), avg);
        float* t = src; src = dst; dst = t;
    };

    launch(epsl[0], 0);                       // init (writes direct)
    for (int k = 0; k < ne; ++k)
        launch(epsl[k], 1);                   // damped symmetric Sinkhorn
    launch(epsl[ne - 1], 0);                  // final extrapolation (writes direct)

    reduce_out<<<dim3(BATCH), THREADS, 0, stream>>>(src, out);
}

// Round 2
// 455.982 us; speedup vs baseline: 4.9681x; 4.9681x over previous
//
#include <hip/hip_runtime.h>
#include <math.h>

// Problem constants (B=8 batches, N=M=2048 points, D=3)
#define BATCH 8
#define NPTS 2048
#define THREADS 256
#define ROWS_PER_BLOCK 64      // 4 waves * 16 rows
#define COLS_PER_GROUP 512     // 2048 cols / 4 col-groups per wave
#define LOG_M 7.62559580411076f   // log(2048)
#define LOG2E 1.4426950408889634f

// One softmin pass, all 4 potential types x 8 batches in one grid:
//   f_i = 0.5*|x_i|^2 - eps * LSE_j( hh_j + x_i . (y_j/eps) )
//   hh_j = pot_j/eps - log(M) - 0.5*|y_j|^2/eps
// Lane layout: lane = (row_local 0..15) + 16*(col_group 0..3). Each lane
// computes one row over 512 columns; col float4s broadcast across the 16
// lanes of a row group. Two passes (max, then exp) recompute the 3-FMA arg
// instead of keeping a per-lane args[] array -> no scratch spill.
// Col groups are skewed by one float4 per 512 slots -> conflict-free LDS.
__global__ __launch_bounds__(THREADS) void softmin_pass(
    const float* __restrict__ x, const float* __restrict__ y,
    const float* __restrict__ potSrc, float* __restrict__ potDst,
    float eps, float inv_eps, int avg)
{
    __shared__ float4 cols[NPTS + 4];   // +1 float4 skew per 512-col group

    const int type  = blockIdx.z;
    const int batch = blockIdx.y;

    const float* rowP;
    const float* colP;
    int hslot, oslot;
    if (type == 0)      { rowP = x; colP = y; hslot = 1; oslot = 0; }  // f_ba
    else if (type == 1) { rowP = y; colP = x; hslot = 0; oslot = 1; }  // g_ab
    else if (type == 2) { rowP = x; colP = x; hslot = 2; oslot = 2; }  // f_aa
    else                { rowP = y; colP = y; hslot = 3; oslot = 3; }  // g_bb

    rowP += batch * NPTS * 3;
    colP += batch * NPTS * 3;
    const float* hP   = potSrc + (hslot * BATCH + batch) * NPTS;
    const float* oldP = potSrc + (oslot * BATCH + batch) * NPTS;
    float*       outP = potDst + (oslot * BATCH + batch) * NPTS;

    // Stage columns in LDS, pre-scaled by 1/eps, hh fused, skewed by j>>9.
    for (int j = threadIdx.x; j < NPTS; j += THREADS) {
        float c0 = colP[3 * j + 0];
        float c1 = colP[3 * j + 1];
        float c2 = colP[3 * j + 2];
        float hh = hP[j] * inv_eps - LOG_M
                 - 0.5f * inv_eps * (c0 * c0 + c1 * c1 + c2 * c2);
        cols[j + (j >> 9)] = make_float4(c0 * inv_eps, c1 * inv_eps, c2 * inv_eps, hh);
    }
    __syncthreads();

    const int lane = threadIdx.x & 63;
    const int wave = threadIdx.x >> 6;
    const int g    = lane >> 4;                               // col group 0..3
    const int i    = blockIdx.x * ROWS_PER_BLOCK + wave * 16 + (lane & 15);

    const float x0 = rowP[3 * i + 0];
    const float x1v = rowP[3 * i + 1];
    const float x2v = rowP[3 * i + 2];
    const float4* gp = &cols[g * (COLS_PER_GROUP + 1)];       // skewed group base

    // ---- pass 1: row max (2 accumulators to break the dep chain) ----
    float m0 = -INFINITY, m1 = -INFINITY;
    #pragma unroll 8
    for (int t = 0; t < COLS_PER_GROUP; t += 2) {
        float4 ca = gp[t];
        float4 cb = gp[t + 1];
        float aa = __builtin_fmaf(x0, ca.x, __builtin_fmaf(x1v, ca.y,
                     __builtin_fmaf(x2v, ca.z, ca.w)));
        float ab = __builtin_fmaf(x0, cb.x, __builtin_fmaf(x1v, cb.y,
                     __builtin_fmaf(x2v, cb.z, cb.w)));
        m0 = fmaxf(m0, aa);
        m1 = fmaxf(m1, ab);
    }
    float m = fmaxf(m0, m1);
    m = fmaxf(m, __shfl_xor(m, 16, 64));   // reduce across the 4 col groups
    m = fmaxf(m, __shfl_xor(m, 32, 64));

    // ---- pass 2: sum of exp2((a - m) * log2e), recomputing a ----
    const float ml = m * LOG2E;
    float s0 = 0.0f, s1 = 0.0f;
    #pragma unroll 8
    for (int t = 0; t < COLS_PER_GROUP; t += 2) {
        float4 ca = gp[t];
        float4 cb = gp[t + 1];
        float aa = __builtin_fmaf(x0, ca.x, __builtin_fmaf(x1v, ca.y,
                     __builtin_fmaf(x2v, ca.z, ca.w)));
        float ab = __builtin_fmaf(x0, cb.x, __builtin_fmaf(x1v, cb.y,
                     __builtin_fmaf(x2v, cb.z, cb.w)));
        s0 += __builtin_amdgcn_exp2f(__builtin_fmaf(aa, LOG2E, -ml));
        s1 += __builtin_amdgcn_exp2f(__builtin_fmaf(ab, LOG2E, -ml));
    }
    float s = s0 + s1;
    s += __shfl_xor(s, 16, 64);
    s += __shfl_xor(s, 32, 64);

    if (g == 0) {
        float xsq = x0 * x0 + x1v * x1v + x2v * x2v;
        float res = 0.5f * xsq - eps * (m + logf(s));
        outP[i] = avg ? 0.5f * (oldP[i] + res) : res;
    }
}

// out[b] = (1/N) * sum_i (f_ba - f_aa) + (1/M) * sum_j (g_ab - g_bb)
__global__ void reduce_out(const float* __restrict__ pot, float* __restrict__ out)
{
    const int batch = blockIdx.x;
    const float* fba = pot + (0 * BATCH + batch) * NPTS;
    const float* gab = pot + (1 * BATCH + batch) * NPTS;
    const float* faa = pot + (2 * BATCH + batch) * NPTS;
    const float* gbb = pot + (3 * BATCH + batch) * NPTS;

    float s = 0.0f;
    for (int i = threadIdx.x; i < NPTS; i += blockDim.x)
        s += (fba[i] - faa[i]) + (gab[i] - gbb[i]);

    #pragma unroll
    for (int off = 32; off >= 1; off >>= 1)
        s += __shfl_xor(s, off, 64);

    __shared__ float red[THREADS / 64];
    const int lane = threadIdx.x & 63;
    const int wave = threadIdx.x >> 6;
    if (lane == 0) red[wave] = s;
    __syncthreads();
    if (threadIdx.x == 0) {
        float t = 0.0f;
        for (int w = 0; w < THREADS / 64; ++w) t += red[w];
        out[batch] = t * (1.0f / NPTS);
    }
}

extern "C" void kernel_launch(void* const* d_in, const int* in_sizes, int n_in,
                              void* d_out, int out_size, void* d_ws, size_t ws_size,
                              hipStream_t stream)
{
    const float* x = (const float*)d_in[0];
    const float* y = (const float*)d_in[1];
    float* out = (float*)d_out;

    // Ping-pong potential buffers in workspace: [4 slots][B][NPTS] each.
    const size_t potElems = (size_t)4 * BATCH * NPTS;
    float* P0 = (float*)d_ws;
    float* P1 = P0 + potElems;

    // Zero the initial potentials (h = a_log exactly at init).
    hipMemsetAsync(P0, 0, potElems * sizeof(float), stream);

    // Epsilon schedule: [diam^p] + exp(arange(p ln diam, p ln blur, p ln scale)) + [blur^p]
    double epsl[16];
    int ne = 0;
    epsl[ne++] = 4.0;                       // diameter^2
    const double stop = 2.0 * log(0.05);
    const double step = 2.0 * log(0.5);
    for (double e = 2.0 * log(2.0); e > stop; e += step)
        epsl[ne++] = exp(e);                // 4, 1, 0.25, 0.0625, 0.015625, 0.00390625
    epsl[ne++] = 0.05 * 0.05;               // blur^2 = 0.0025

    float* src = P0;
    float* dst = P1;
    dim3 grid(NPTS / ROWS_PER_BLOCK, BATCH, 4);

    auto launch = [&](double eps, int avg) {
        softmin_pass<<<grid, THREADS, 0, stream>>>(
            x, y, src, dst, (float)eps, (float)(1.0 / eps), avg);
        float* t = src; src = dst; dst = t;
    };

    launch(epsl[0], 0);                       // init (writes direct)
    for (int k = 0; k < ne; ++k)
        launch(epsl[k], 1);                   // damped symmetric Sinkhorn
    launch(epsl[ne - 1], 0);                  // final extrapolation (writes direct)

    reduce_out<<<dim3(BATCH), THREADS, 0, stream>>>(src, out);
}

// Round 3
// 408.830 us; speedup vs baseline: 5.5411x; 1.1153x over previous
//
#include <hip/hip_runtime.h>
#include <math.h>

// Problem constants (B=8 batches, N=M=2048 points, D=3)
#define BATCH 8
#define NPTS 2048
#define THREADS 256
#define NG 16                  // col groups per wave (lane>>2)
#define CPG 128                // cols per group (2048/16)
#define RPL 4                  // rows per lane
#define ROWS_PER_WAVE 16       // 4 slots * 4 rows
#define ROWS_PER_BLOCK 64      // 4 waves
#define LOG_M 7.62559580411076f   // log(2048)
#define LOG2E 1.4426950408889634f

// One softmin pass, all 4 potential types x 8 batches in one grid:
//   f_i = 0.5*|x_i|^2 - eps * LSE_j( hh_j + x_i . (y_j/eps) )
//   hh_j = pot_j/eps - log(M) - 0.5*|y_j|^2/eps
// Lane layout: lane = (row_slot 0..3) + 4*(col_group 0..15). Each lane
// computes 4 rows (i0, i0+4, i0+8, i0+12) over its group's 128 columns, so
// one ds_read_b128 is amortized over 4 rows (16 FMA-class VALU ops per read)
// -> LDS pipe drops from binding (~41 us) to ~10 us; VALU (~22 us) binds.
// Two passes (max, then exp) recompute the 3-FMA arg -> no spill.
// Groups skewed by +1 float4 per 128 cols -> bank offset 4g mod 32 ->
// at most 2-way aliasing (free).
__global__ __launch_bounds__(THREADS) void softmin_pass(
    const float* __restrict__ x, const float* __restrict__ y,
    const float* __restrict__ potSrc, float* __restrict__ potDst,
    float eps, float inv_eps, int avg)
{
    __shared__ float4 cols[NPTS + NG];   // +1 float4 skew per group

    const int type  = blockIdx.z;
    const int batch = blockIdx.y;

    const float* rowP;
    const float* colP;
    int hslot, oslot;
    if (type == 0)      { rowP = x; colP = y; hslot = 1; oslot = 0; }  // f_ba
    else if (type == 1) { rowP = y; colP = x; hslot = 0; oslot = 1; }  // g_ab
    else if (type == 2) { rowP = x; colP = x; hslot = 2; oslot = 2; }  // f_aa
    else                { rowP = y; colP = y; hslot = 3; oslot = 3; }  // g_bb

    rowP += batch * NPTS * 3;
    colP += batch * NPTS * 3;
    const float* hP   = potSrc + (hslot * BATCH + batch) * NPTS;
    const float* oldP = potSrc + (oslot * BATCH + batch) * NPTS;
    float*       outP = potDst + (oslot * BATCH + batch) * NPTS;

    // Stage columns in LDS, pre-scaled by 1/eps, hh fused, skewed by j>>7.
    for (int j = threadIdx.x; j < NPTS; j += THREADS) {
        float c0 = colP[3 * j + 0];
        float c1 = colP[3 * j + 1];
        float c2 = colP[3 * j + 2];
        float hh = hP[j] * inv_eps - LOG_M
                 - 0.5f * inv_eps * (c0 * c0 + c1 * c1 + c2 * c2);
        cols[j + (j >> 7)] = make_float4(c0 * inv_eps, c1 * inv_eps, c2 * inv_eps, hh);
    }
    __syncthreads();

    const int lane = threadIdx.x & 63;
    const int wave = threadIdx.x >> 6;
    const int slot = lane & 3;
    const int g    = lane >> 2;
    const int i0   = blockIdx.x * ROWS_PER_BLOCK + wave * ROWS_PER_WAVE + slot;

    // 4 rows per lane: i0, i0+4, i0+8, i0+12
    float rx[RPL], ry[RPL], rz[RPL];
    #pragma unroll
    for (int k = 0; k < RPL; ++k) {
        const int i = i0 + 4 * k;
        rx[k] = rowP[3 * i + 0];
        ry[k] = rowP[3 * i + 1];
        rz[k] = rowP[3 * i + 2];
    }

    const float4* gp = &cols[g * (CPG + 1)];   // skewed group base

    // ---- pass 1: row maxes over this lane's 128 cols ----
    float m[RPL];
    #pragma unroll
    for (int k = 0; k < RPL; ++k) m[k] = -INFINITY;
    #pragma unroll 4
    for (int t = 0; t < CPG; ++t) {
        float4 c = gp[t];
        #pragma unroll
        for (int k = 0; k < RPL; ++k) {
            float a = __builtin_fmaf(rx[k], c.x, __builtin_fmaf(ry[k], c.y,
                        __builtin_fmaf(rz[k], c.z, c.w)));
            m[k] = fmaxf(m[k], a);
        }
    }
    // reduce maxes across the 16 col groups (same slot = same rows)
    #pragma unroll
    for (int off = 4; off <= 32; off <<= 1) {
        #pragma unroll
        for (int k = 0; k < RPL; ++k)
            m[k] = fmaxf(m[k], __shfl_xor(m[k], off, 64));
    }

    // ---- pass 2: sum of exp2((a - m) * log2e), recomputing a ----
    float ml[RPL], s[RPL];
    #pragma unroll
    for (int k = 0; k < RPL; ++k) { ml[k] = m[k] * LOG2E; s[k] = 0.0f; }
    #pragma unroll 4
    for (int t = 0; t < CPG; ++t) {
        float4 c = gp[t];
        #pragma unroll
        for (int k = 0; k < RPL; ++k) {
            float a = __builtin_fmaf(rx[k], c.x, __builtin_fmaf(ry[k], c.y,
                        __builtin_fmaf(rz[k], c.z, c.w)));
            s[k] += __builtin_amdgcn_exp2f(__builtin_fmaf(a, LOG2E, -ml[k]));
        }
    }
    #pragma unroll
    for (int off = 4; off <= 32; off <<= 1) {
        #pragma unroll
        for (int k = 0; k < RPL; ++k)
            s[k] += __shfl_xor(s[k], off, 64);
    }

    if (g == 0) {
        #pragma unroll
        for (int k = 0; k < RPL; ++k) {
            const int i = i0 + 4 * k;
            float xsq = rx[k] * rx[k] + ry[k] * ry[k] + rz[k] * rz[k];
            float res = 0.5f * xsq - eps * (m[k] + logf(s[k]));
            outP[i] = avg ? 0.5f * (oldP[i] + res) : res;
        }
    }
}

// out[b] = (1/N) * sum_i (f_ba - f_aa) + (1/M) * sum_j (g_ab - g_bb)
__global__ void reduce_out(const float* __restrict__ pot, float* __restrict__ out)
{
    const int batch = blockIdx.x;
    const float* fba = pot + (0 * BATCH + batch) * NPTS;
    const float* gab = pot + (1 * BATCH + batch) * NPTS;
    const float* faa = pot + (2 * BATCH + batch) * NPTS;
    const float* gbb = pot + (3 * BATCH + batch) * NPTS;

    float s = 0.0f;
    for (int i = threadIdx.x; i < NPTS; i += blockDim.x)
        s += (fba[i] - faa[i]) + (gab[i] - gbb[i]);

    #pragma unroll
    for (int off = 32; off >= 1; off >>= 1)
        s += __shfl_xor(s, off, 64);

    __shared__ float red[THREADS / 64];
    const int lane = threadIdx.x & 63;
    const int wave = threadIdx.x >> 6;
    if (lane == 0) red[wave] = s;
    __syncthreads();
    if (threadIdx.x == 0) {
        float t = 0.0f;
        for (int w = 0; w < THREADS / 64; ++w) t += red[w];
        out[batch] = t * (1.0f / NPTS);
    }
}

extern "C" void kernel_launch(void* const* d_in, const int* in_sizes, int n_in,
                              void* d_out, int out_size, void* d_ws, size_t ws_size,
                              hipStream_t stream)
{
    const float* x = (const float*)d_in[0];
    const float* y = (const float*)d_in[1];
    float* out = (float*)d_out;

    // Ping-pong potential buffers in workspace: [4 slots][B][NPTS] each.
    const size_t potElems = (size_t)4 * BATCH * NPTS;
    float* P0 = (float*)d_ws;
    float* P1 = P0 + potElems;

    // Zero the initial potentials (h = a_log exactly at init).
    hipMemsetAsync(P0, 0, potElems * sizeof(float), stream);

    // Epsilon schedule: [diam^p] + exp(arange(p ln diam, p ln blur, p ln scale)) + [blur^p]
    double epsl[16];
    int ne = 0;
    epsl[ne++] = 4.0;                       // diameter^2
    const double stop = 2.0 * log(0.05);
    const double step = 2.0 * log(0.5);
    for (double e = 2.0 * log(2.0); e > stop; e += step)
        epsl[ne++] = exp(e);                // 4, 1, 0.25, 0.0625, 0.015625, 0.00390625
    epsl[ne++] = 0.05 * 0.05;               // blur^2 = 0.0025

    float* src = P0;
    float* dst = P1;
    dim3 grid(NPTS / ROWS_PER_BLOCK, BATCH, 4);

    auto launch = [&](double eps, int avg) {
        softmin_pass<<<grid, THREADS, 0, stream>>>(
            x, y, src, dst, (float)eps, (float)(1.0 / eps), avg);
        float* t = src; src = dst; dst = t;
    };

    launch(epsl[0], 0);                       // init (writes direct)
    for (int k = 0; k < ne; ++k)
        launch(epsl[k], 1);                   // damped symmetric Sinkhorn
    launch(epsl[ne - 1], 0);                  // final extrapolation (writes direct)

    reduce_out<<<dim3(BATCH), THREADS, 0, stream>>>(src, out);
}